// Round 1
// baseline (5478.932 us; speedup 1.0000x reference)
//
#include <hip/hip_runtime.h>
#include <hip/hip_bf16.h>

// GPT-2 small forward: L=12, H=12, E=768, V=50257, B=2, T=1024, HS=64
// All fp32 in/out; internal GEMMs via bf16 MFMA (16x16x32), fp32 accumulate.

typedef __bf16 bf16x8 __attribute__((ext_vector_type(8)));
typedef float f32x4 __attribute__((ext_vector_type(4)));
typedef unsigned int u32x4 __attribute__((ext_vector_type(4)));

__device__ inline unsigned short f2bf(float f) {
    unsigned int u = __float_as_uint(f);
    u += 0x7FFFu + ((u >> 16) & 1u);   // round-to-nearest-even
    return (unsigned short)(u >> 16);
}
__device__ inline unsigned int pk2(float a, float b) {
    return (unsigned int)f2bf(a) | ((unsigned int)f2bf(b) << 16);
}
__device__ inline float gelu_f(float v) {
    return 0.5f * v * (1.0f + erff(v * 0.70710678118654752f));
}

// ---------------------------------------------------------------- embedding
__global__ __launch_bounds__(192) void embed_kernel(
    const int* __restrict__ idx, const float* __restrict__ wte,
    const float* __restrict__ wpe, float* __restrict__ x) {
    int row = blockIdx.x;            // 0..2047  (b*1024+t)
    int t = row & 1023;
    int tok = idx[row];
    const float4* src = (const float4*)(wte + (size_t)tok * 768);
    const float4* pe  = (const float4*)(wpe + (size_t)t * 768);
    float4* dst = (float4*)(x + (size_t)row * 768);
    int i = threadIdx.x;             // 192 threads * 4 floats = 768
    float4 a = src[i], b = pe[i];
    float4 r; r.x = a.x + b.x; r.y = a.y + b.y; r.z = a.z + b.z; r.w = a.w + b.w;
    dst[i] = r;
}

// ---------------------------------------------------------------- layernorm
__global__ __launch_bounds__(256) void ln_kernel(
    const float* __restrict__ in, const float* __restrict__ w,
    const float* __restrict__ b, float* __restrict__ out) {
    int row = blockIdx.x;
    const float* r = in + (size_t)row * 768;
    int tid = threadIdx.x;
    float v[3];
#pragma unroll
    for (int j = 0; j < 3; j++) v[j] = r[tid + j * 256];
    float s = v[0] + v[1] + v[2];
    __shared__ float sh1[4], sh2[4];
#pragma unroll
    for (int o = 32; o; o >>= 1) s += __shfl_down(s, o);
    if ((tid & 63) == 0) sh1[tid >> 6] = s;
    __syncthreads();
    float mean = (sh1[0] + sh1[1] + sh1[2] + sh1[3]) * (1.0f / 768.0f);
    float d0 = v[0] - mean, d1 = v[1] - mean, d2 = v[2] - mean;
    float sq = d0 * d0 + d1 * d1 + d2 * d2;
#pragma unroll
    for (int o = 32; o; o >>= 1) sq += __shfl_down(sq, o);
    if ((tid & 63) == 0) sh2[tid >> 6] = sq;
    __syncthreads();
    float var = (sh2[0] + sh2[1] + sh2[2] + sh2[3]) * (1.0f / 768.0f);
    float rstd = rsqrtf(var + 1e-5f);
#pragma unroll
    for (int j = 0; j < 3; j++) {
        int c = tid + j * 256;
        out[(size_t)row * 768 + c] = (v[j] - mean) * rstd * w[c] + b[c];
    }
}

// ------------------------------------------------------- causal softmax (T=1024)
__global__ __launch_bounds__(256) void softmax_kernel(float* __restrict__ S) {
    int gr = blockIdx.x;             // (b*H+h)*1024 + q
    int q = gr & 1023;
    float* row = S + (size_t)gr * 1024;
    int tid = threadIdx.x;
    float v[4];
    float m = -1e30f;
#pragma unroll
    for (int j = 0; j < 4; j++) {
        int k = tid + j * 256;
        v[j] = row[k];
        if (k <= q) m = fmaxf(m, v[j]);
    }
    __shared__ float shm[4], shs[4];
#pragma unroll
    for (int o = 32; o; o >>= 1) m = fmaxf(m, __shfl_down(m, o));
    if ((tid & 63) == 0) shm[tid >> 6] = m;
    __syncthreads();
    m = fmaxf(fmaxf(shm[0], shm[1]), fmaxf(shm[2], shm[3]));
    const float f = 0.125f * 1.4426950408889634f;   // scale * log2(e)
    float s = 0.0f;
#pragma unroll
    for (int j = 0; j < 4; j++) {
        int k = tid + j * 256;
        v[j] = (k <= q) ? exp2f((v[j] - m) * f) : 0.0f;
        s += v[j];
    }
#pragma unroll
    for (int o = 32; o; o >>= 1) s += __shfl_down(s, o);
    if ((tid & 63) == 0) shs[tid >> 6] = s;
    __syncthreads();
    s = shs[0] + shs[1] + shs[2] + shs[3];
    float inv = 1.0f / s;
#pragma unroll
    for (int j = 0; j < 4; j++) row[tid + j * 256] = v[j] * inv;
}

// ---------------------------------------------------------------- GEMM
// C[M,N] = A[M,K] @ B + bias (+ residual / gelu).  BM=128 fixed, BK=32.
// BT=false: B is [K,N] row-major (ldb = row stride).
// BT=true : B is [N,K] row-major (weights-as-rows; bounds-checked on N).
// EPI: 0 = bias only, 1 = bias+gelu, 2 = bias+residual(R).
// CK: causal attention helper (skip fully masked score tiles; limit K to brow+128).
// Batched: z -> (z1 = z/Z2, z2 = z%Z2), offsets applied to A/B/C (and R==C base).
template <int BN, bool BT, int EPI, bool CK>
__global__ __launch_bounds__(256) void gemm_kernel(
    const float* __restrict__ A, int lda, long long sAz1, long long sAz2,
    const float* __restrict__ B, int ldb, long long sBz1, long long sBz2,
    float* __restrict__ C, int ldc, long long sCz1, long long sCz2,
    const float* __restrict__ bias, const float* __restrict__ R,
    int M, int N, int K, int Z2) {
    constexpr int FM = 4;            // 64 rows per wave
    constexpr int FN = BN / 32;      // 64 or 32 cols per wave
    constexpr int LDS_W = 40;        // 32 + 8 pad (bf16 elems)

    int brow = blockIdx.y * 128;
    int bcol = blockIdx.x * BN;
    if (CK && bcol >= brow + 128) return;      // fully causal-masked tile
    int Klim = CK ? (K < brow + 128 ? K : brow + 128) : K;

    int z = blockIdx.z;
    int z1 = z / Z2, z2 = z % Z2;
    A += z1 * sAz1 + z2 * sAz2;
    B += z1 * sBz1 + z2 * sBz2;
    C += z1 * sCz1 + z2 * sCz2;
    const float* Rp = R ? R + z1 * sCz1 + z2 * sCz2 : nullptr;

    __shared__ unsigned short Asm[128][LDS_W];
    __shared__ unsigned short Bsm[BN][LDS_W];

    int tid = threadIdx.x;
    int lane = tid & 63, wid = tid >> 6;
    int wr = (wid >> 1) * 64;
    int wc = (wid & 1) * (FN * 16);
    int fr = lane & 15;              // fragment row/col
    int kg = (lane >> 4) * 8;        // k-offset within 32

    f32x4 acc[FM][FN] = {};

    for (int k0 = 0; k0 < Klim; k0 += 32) {
        __syncthreads();
        // ---- stage A: 128 rows x 32 k, 2 threads/row, 16 elems each
        {
            int ar = tid >> 1;
            int kk = (tid & 1) << 4;
            const float* src = A + (size_t)(brow + ar) * lda + k0 + kk;
            float4 f0 = *(const float4*)(src);
            float4 f1 = *(const float4*)(src + 4);
            float4 f2 = *(const float4*)(src + 8);
            float4 f3 = *(const float4*)(src + 12);
            u32x4 u0 = {pk2(f0.x, f0.y), pk2(f0.z, f0.w), pk2(f1.x, f1.y), pk2(f1.z, f1.w)};
            u32x4 u1 = {pk2(f2.x, f2.y), pk2(f2.z, f2.w), pk2(f3.x, f3.y), pk2(f3.z, f3.w)};
            *reinterpret_cast<u32x4*>(&Asm[ar][kk]) = u0;
            *reinterpret_cast<u32x4*>(&Asm[ar][kk + 8]) = u1;
        }
        // ---- stage B
        if (BT) {
            // B is [N,K]: same pattern as A, with N bounds check (BN==128 here)
            int nr = tid >> 1;
            int kk = (tid & 1) << 4;
            bool ok = (bcol + nr) < N;
            const float* src = B + (size_t)(bcol + nr) * ldb + k0 + kk;
            float4 f0, f1, f2, f3;
            if (ok) {
                f0 = *(const float4*)(src);
                f1 = *(const float4*)(src + 4);
                f2 = *(const float4*)(src + 8);
                f3 = *(const float4*)(src + 12);
            } else {
                f0 = f1 = f2 = f3 = float4{0.f, 0.f, 0.f, 0.f};
            }
            u32x4 u0 = {pk2(f0.x, f0.y), pk2(f0.z, f0.w), pk2(f1.x, f1.y), pk2(f1.z, f1.w)};
            u32x4 u1 = {pk2(f2.x, f2.y), pk2(f2.z, f2.w), pk2(f3.x, f3.y), pk2(f3.z, f3.w)};
            *reinterpret_cast<u32x4*>(&Bsm[nr][kk]) = u0;
            *reinterpret_cast<u32x4*>(&Bsm[nr][kk + 8]) = u1;
        } else {
            // B is [K,N]: 32 k-rows, 8 threads/row, BN/8 contiguous n each; transpose into LDS
            constexpr int NPT = BN / 8;          // 16 or 8
            int kr = tid >> 3;
            int j0 = (tid & 7) * NPT;
            const float* src = B + (size_t)(k0 + kr) * ldb + bcol + j0;
            float vals[NPT];
#pragma unroll
            for (int j = 0; j < NPT / 4; j++) {
                float4 f = *(const float4*)(src + j * 4);
                vals[j * 4 + 0] = f.x; vals[j * 4 + 1] = f.y;
                vals[j * 4 + 2] = f.z; vals[j * 4 + 3] = f.w;
            }
#pragma unroll
            for (int j = 0; j < NPT; j++) Bsm[j0 + j][kr] = f2bf(vals[j]);
        }
        __syncthreads();

        // ---- fragments + MFMA
        bf16x8 af[FM], bfr[FN];
#pragma unroll
        for (int m = 0; m < FM; m++)
            af[m] = *reinterpret_cast<const bf16x8*>(&Asm[wr + m * 16 + fr][kg]);
#pragma unroll
        for (int n = 0; n < FN; n++)
            bfr[n] = *reinterpret_cast<const bf16x8*>(&Bsm[wc + n * 16 + fr][kg]);
#pragma unroll
        for (int m = 0; m < FM; m++)
#pragma unroll
            for (int n = 0; n < FN; n++)
                acc[m][n] = __builtin_amdgcn_mfma_f32_16x16x32_bf16(af[m], bfr[n], acc[m][n], 0, 0, 0);
    }

    // ---- epilogue
    int cr = (lane >> 4) * 4;
#pragma unroll
    for (int m = 0; m < FM; m++) {
#pragma unroll
        for (int n = 0; n < FN; n++) {
            int col = bcol + wc + n * 16 + fr;
            if (BT && col >= N) continue;
            float bv = bias ? bias[col] : 0.0f;
#pragma unroll
            for (int i = 0; i < 4; i++) {
                int row = brow + wr + m * 16 + cr + i;
                float v = acc[m][n][i] + bv;
                if constexpr (EPI == 1) v = gelu_f(v);
                if constexpr (EPI == 2) v += Rp[(size_t)row * ldc + col];
                C[(size_t)row * ldc + col] = v;
            }
        }
    }
}

// ---------------------------------------------------------------- launch
extern "C" void kernel_launch(void* const* d_in, const int* in_sizes, int n_in,
                              void* d_out, int out_size, void* d_ws, size_t ws_size,
                              hipStream_t stream) {
    const int*   idx    = (const int*)d_in[0];
    const float* wte    = (const float*)d_in[1];
    const float* wpe    = (const float*)d_in[2];
    const float* ln1_w  = (const float*)d_in[3];
    const float* ln1_b  = (const float*)d_in[4];
    const float* attn_w = (const float*)d_in[5];
    const float* attn_b = (const float*)d_in[6];
    const float* proj_w = (const float*)d_in[7];
    const float* proj_b = (const float*)d_in[8];
    const float* ln2_w  = (const float*)d_in[9];
    const float* ln2_b  = (const float*)d_in[10];
    const float* fc_w   = (const float*)d_in[11];
    const float* fc_b   = (const float*)d_in[12];
    const float* fcp_w  = (const float*)d_in[13];
    const float* fcp_b  = (const float*)d_in[14];
    const float* lnf_w  = (const float*)d_in[15];
    const float* lnf_b  = (const float*)d_in[16];
    float* out = (float*)d_out;

    float* ws  = (float*)d_ws;
    float* x   = ws;                         // 2048*768
    float* xn  = x + 2048 * 768;             // 2048*768
    float* qkv = xn + 2048 * 768;            // 2048*2304
    float* y   = qkv + 2048 * 2304;          // 2048*768
    float* h   = y + 2048 * 768;             // 2048*3072
    float* S   = h + 2048 * 3072;            // 24*1024*1024

    const long long sQKV = 1024LL * 2304;    // per-batch stride inside qkv
    const long long sS1 = 12LL * 1024 * 1024, sS2 = 1024LL * 1024;

    embed_kernel<<<2048, 192, 0, stream>>>(idx, wte, wpe, x);

    for (int l = 0; l < 12; l++) {
        ln_kernel<<<2048, 256, 0, stream>>>(x, ln1_w + l * 768, ln1_b + l * 768, xn);
        // qkv = xn @ attn_w + attn_b   [2048,2304]
        gemm_kernel<128, false, 0, false><<<dim3(18, 16, 1), 256, 0, stream>>>(
            xn, 768, 0, 0,
            attn_w + (size_t)l * 768 * 2304, 2304, 0, 0,
            qkv, 2304, 0, 0,
            attn_b + l * 2304, nullptr, 2048, 2304, 768, 1);
        // S = Q @ K^T   per (b,h): M=N=1024, K=64
        gemm_kernel<128, true, 0, true><<<dim3(8, 8, 24), 256, 0, stream>>>(
            qkv, 2304, sQKV, 64,
            qkv + 768, 2304, sQKV, 64,
            S, 1024, sS1, sS2,
            nullptr, nullptr, 1024, 1024, 64, 12);
        softmax_kernel<<<24 * 1024, 256, 0, stream>>>(S);
        // y = P @ V     per (b,h): M=1024, N=64, K=1024 (K limited causally)
        gemm_kernel<64, false, 0, true><<<dim3(1, 8, 24), 256, 0, stream>>>(
            S, 1024, sS1, sS2,
            qkv + 1536, 2304, sQKV, 64,
            y, 768, 1024LL * 768, 64,
            nullptr, nullptr, 1024, 64, 1024, 12);
        // x = x + y @ proj_w + proj_b
        gemm_kernel<128, false, 2, false><<<dim3(6, 16, 1), 256, 0, stream>>>(
            y, 768, 0, 0,
            proj_w + (size_t)l * 768 * 768, 768, 0, 0,
            x, 768, 0, 0,
            proj_b + l * 768, x, 2048, 768, 768, 1);
        ln_kernel<<<2048, 256, 0, stream>>>(x, ln2_w + l * 768, ln2_b + l * 768, xn);
        // h = gelu(xn @ fc_w + fc_b)   [2048,3072]
        gemm_kernel<128, false, 1, false><<<dim3(24, 16, 1), 256, 0, stream>>>(
            xn, 768, 0, 0,
            fc_w + (size_t)l * 768 * 3072, 3072, 0, 0,
            h, 3072, 0, 0,
            fc_b + l * 3072, nullptr, 2048, 3072, 768, 1);
        // x = x + h @ fcp_w + fcp_b
        gemm_kernel<128, false, 2, false><<<dim3(6, 16, 1), 256, 0, stream>>>(
            h, 3072, 0, 0,
            fcp_w + (size_t)l * 3072 * 768, 768, 0, 0,
            x, 768, 0, 0,
            fcp_b + l * 768, x, 2048, 768, 3072, 1);
    }
    ln_kernel<<<2048, 256, 0, stream>>>(x, lnf_w, lnf_b, xn);
    // logits = xn @ wte^T   [2048, 50257]
    gemm_kernel<128, true, 0, false><<<dim3(393, 16, 1), 256, 0, stream>>>(
        xn, 768, 0, 0,
        wte, 768, 0, 0,
        out, 50257, 0, 0,
        nullptr, nullptr, 2048, 50257, 768, 1);
}

// Round 4
// 3365.097 us; speedup vs baseline: 1.6282x; 1.6282x over previous
//
#include <hip/hip_runtime.h>
#include <hip/hip_bf16.h>

// GPT-2 small forward: L=12, H=12, E=768, V=50257, B=2, T=1024, HS=64
// fp32 in/out; internal: bf16 storage + MFMA 16x16x32, fp32 accumulate.
// GEMM v2: m97 structure — global_load_lds(16B) -> linear LDS -> ds_read_b128.
// Weights transposed to [N,K] bf16 per layer (small per-layer buffers).

typedef __bf16 bf16x8 __attribute__((ext_vector_type(8)));
typedef float f32x4 __attribute__((ext_vector_type(4)));
typedef unsigned int u32x4 __attribute__((ext_vector_type(4)));
typedef unsigned short ushort_t;

__device__ inline unsigned short f2bf(float f) {
    unsigned int u = __float_as_uint(f);
    u += 0x7FFFu + ((u >> 16) & 1u);   // round-to-nearest-even
    return (unsigned short)(u >> 16);
}
__device__ inline unsigned int pk2(float a, float b) {
    return (unsigned int)f2bf(a) | ((unsigned int)f2bf(b) << 16);
}
__device__ inline float gelu_f(float v) {
    return 0.5f * v * (1.0f + erff(v * 0.70710678118654752f));
}
__device__ inline void gld16(const ushort_t* g, ushort_t* l) {
    __builtin_amdgcn_global_load_lds(
        (const __attribute__((address_space(1))) void*)g,
        (__attribute__((address_space(3))) void*)l, 16, 0, 0);
}
__device__ inline void store_c(float* p, float v) { *p = v; }
__device__ inline void store_c(ushort_t* p, float v) { *p = f2bf(v); }

// ---------------------------------------------------------------- embedding
__global__ __launch_bounds__(192) void embed_kernel(
    const int* __restrict__ idx, const float* __restrict__ wte,
    const float* __restrict__ wpe, float* __restrict__ x) {
    int row = blockIdx.x;            // b*1024+t
    int t = row & 1023;
    int tok = idx[row];
    const float4* src = (const float4*)(wte + (size_t)tok * 768);
    const float4* pe  = (const float4*)(wpe + (size_t)t * 768);
    float4* dst = (float4*)(x + (size_t)row * 768);
    int i = threadIdx.x;
    float4 a = src[i], b = pe[i];
    float4 r; r.x = a.x + b.x; r.y = a.y + b.y; r.z = a.z + b.z; r.w = a.w + b.w;
    dst[i] = r;
}

// ------------------------------------------------- layernorm (fp32 in, bf16 out)
__global__ __launch_bounds__(256) void ln_kernel(
    const float* __restrict__ in, const float* __restrict__ w,
    const float* __restrict__ b, ushort_t* __restrict__ out) {
    int row = blockIdx.x;
    const float* r = in + (size_t)row * 768;
    int tid = threadIdx.x;
    float v[3];
#pragma unroll
    for (int j = 0; j < 3; j++) v[j] = r[tid + j * 256];
    float s = v[0] + v[1] + v[2];
    __shared__ float sh1[4], sh2[4];
#pragma unroll
    for (int o = 32; o; o >>= 1) s += __shfl_down(s, o);
    if ((tid & 63) == 0) sh1[tid >> 6] = s;
    __syncthreads();
    float mean = (sh1[0] + sh1[1] + sh1[2] + sh1[3]) * (1.0f / 768.0f);
    float d0 = v[0] - mean, d1 = v[1] - mean, d2 = v[2] - mean;
    float sq = d0 * d0 + d1 * d1 + d2 * d2;
#pragma unroll
    for (int o = 32; o; o >>= 1) sq += __shfl_down(sq, o);
    if ((tid & 63) == 0) sh2[tid >> 6] = sq;
    __syncthreads();
    float var = (sh2[0] + sh2[1] + sh2[2] + sh2[3]) * (1.0f / 768.0f);
    float rstd = rsqrtf(var + 1e-5f);
#pragma unroll
    for (int j = 0; j < 3; j++) {
        int c = tid + j * 256;
        out[(size_t)row * 768 + c] = f2bf((v[j] - mean) * rstd * w[c] + b[c]);
    }
}

// ---------------- causal softmax: fp32 S row -> bf16 P in-place (first half of row)
__global__ __launch_bounds__(256) void softmax_kernel(float* __restrict__ S) {
    int gr = blockIdx.x;             // (b*H+h)*1024 + q
    int q = gr & 1023;
    float* row = S + (size_t)gr * 1024;
    ushort_t* prow = (ushort_t*)row;
    int tid = threadIdx.x;
    float v[4];
    float m = -1e30f;
#pragma unroll
    for (int j = 0; j < 4; j++) {
        int k = tid + j * 256;
        v[j] = (k <= q) ? row[k] : -1e30f;
        m = fmaxf(m, v[j]);
    }
    __shared__ float shm[4], shs[4];
#pragma unroll
    for (int o = 32; o; o >>= 1) m = fmaxf(m, __shfl_down(m, o));
    if ((tid & 63) == 0) shm[tid >> 6] = m;
    __syncthreads();
    m = fmaxf(fmaxf(shm[0], shm[1]), fmaxf(shm[2], shm[3]));
    const float f = 0.125f * 1.4426950408889634f;   // scale * log2(e)
    float s = 0.0f;
#pragma unroll
    for (int j = 0; j < 4; j++) {
        int k = tid + j * 256;
        v[j] = (k <= q) ? exp2f((v[j] - m) * f) : 0.0f;
        s += v[j];
    }
#pragma unroll
    for (int o = 32; o; o >>= 1) s += __shfl_down(s, o);
    if ((tid & 63) == 0) shs[tid >> 6] = s;
    __syncthreads();
    s = shs[0] + shs[1] + shs[2] + shs[3];
    float inv = 1.0f / s;
#pragma unroll
    for (int j = 0; j < 4; j++) prow[tid + j * 256] = f2bf(v[j] * inv);
}

// ------------------------------------- weight transpose+convert: fp32[K,N] -> bf16[N,K]
__global__ __launch_bounds__(256) void transpose_w(
    const float* __restrict__ in, ushort_t* __restrict__ out, int K, int N) {
    int n0 = blockIdx.x * 64, k0 = blockIdx.y * 64;
    __shared__ float t[64][65];
    int tid = threadIdx.x;
    int r = tid >> 4, c = (tid & 15) * 4;
#pragma unroll
    for (int j = 0; j < 4; j++) {
        float4 v = *(const float4*)(in + (size_t)(k0 + r + j * 16) * N + n0 + c);
        t[r + j * 16][c] = v.x; t[r + j * 16][c + 1] = v.y;
        t[r + j * 16][c + 2] = v.z; t[r + j * 16][c + 3] = v.w;
    }
    __syncthreads();
    int nr = tid >> 2, kc = (tid & 3) * 16;
    unsigned int u[8];
#pragma unroll
    for (int j = 0; j < 8; j++)
        u[j] = pk2(t[kc + 2 * j][nr], t[kc + 2 * j + 1][nr]);
    u32x4 a = {u[0], u[1], u[2], u[3]}, b = {u[4], u[5], u[6], u[7]};
    ushort_t* op = out + (size_t)(n0 + nr) * K + k0 + kc;
    *(u32x4*)op = a;
    *(u32x4*)(op + 8) = b;
}

// --------------------------------------------------- straight fp32 -> bf16 convert
__global__ __launch_bounds__(256) void convert_bf(
    const float* __restrict__ in, ushort_t* __restrict__ out, long long n8) {
    long long i = (long long)blockIdx.x * 256 + threadIdx.x;
    long long stride = (long long)gridDim.x * 256;
    for (; i < n8; i += stride) {
        const float4* s = (const float4*)(in + i * 8);
        float4 a = s[0], b = s[1];
        u32x4 u = {pk2(a.x, a.y), pk2(a.z, a.w), pk2(b.x, b.y), pk2(b.z, b.w)};
        *(u32x4*)(out + i * 8) = u;
    }
}

// ---- V transpose: qkv bf16 [b,t,1536+h*64+f] -> vt[b,h,f,t]
// FIXED (R3 NaN root cause): each thread now loads its FULL 16 ushorts via two
// u32x4 loads (previous version loaded 8 and read 8 undefined values -> NaN).
__global__ __launch_bounds__(256) void vtrans_kernel(
    const ushort_t* __restrict__ qkvb, ushort_t* __restrict__ vt) {
    int t0 = blockIdx.x * 64;
    int z = blockIdx.y;              // b*12+h
    int b = z / 12, hh = z % 12;
    const ushort_t* src = qkvb + (size_t)b * 1024 * 2304 + 1536 + hh * 64;
    ushort_t* dst = vt + (size_t)z * 64 * 1024;
    __shared__ __align__(16) ushort_t tl[64][72];   // 64 t-rows x 64 f-cols (+8 pad)
    int tid = threadIdx.x;
    int r = tid >> 2, c = (tid & 3) * 16;           // row r, cols c..c+15
    const ushort_t* sp = src + (size_t)(t0 + r) * 2304 + c;
    u32x4 v0 = *(const u32x4*)sp;
    u32x4 v1 = *(const u32x4*)(sp + 8);
    *(u32x4*)&tl[r][c] = v0;
    *(u32x4*)&tl[r][c + 8] = v1;
    __syncthreads();
    int f = tid >> 2, tc = (tid & 3) * 16;          // out row f, t-cols tc..tc+15
    unsigned int u[8];
#pragma unroll
    for (int j = 0; j < 8; j++)
        u[j] = (unsigned int)tl[tc + 2 * j][f] | ((unsigned int)tl[tc + 2 * j + 1][f] << 16);
    u32x4 a = {u[0], u[1], u[2], u[3]}, b2 = {u[4], u[5], u[6], u[7]};
    ushort_t* op = dst + (size_t)f * 1024 + t0 + tc;
    *(u32x4*)op = a;
    *(u32x4*)(op + 8) = b2;
}

// ---------------------------------------------------------------- GEMM v2
// C[M,N](+bias/gelu/residual) = A[M,K]bf16 @ B[N,K]bf16^T
// BM=128, BK=32, 256 threads (4 waves, each 64 x FN*16).
// EPI: 0=bias, 1=bias+gelu, 2=bias+residual(fp32 R).  CK: causal skip/limit.
// SWAP: brow from blockIdx.x (lm-head L2 reuse of B panels).
template <int BN, int EPI, bool CK, bool SWAP, typename TC>
__global__ __launch_bounds__(256) void gemm2(
    const ushort_t* __restrict__ A, int lda, long long sAz1, long long sAz2,
    const ushort_t* __restrict__ B, int ldb, long long sBz1, long long sBz2,
    TC* __restrict__ C, int ldc, long long sCz1, long long sCz2,
    const float* __restrict__ bias, const float* __restrict__ R,
    int M, int N, int K, int Z2) {
    constexpr int FN = BN / 32;      // column fragments per wave
    int brow = (SWAP ? blockIdx.x : blockIdx.y) * 128;
    int bcol = (SWAP ? blockIdx.y : blockIdx.x) * BN;
    if (CK && bcol >= brow + 128) return;
    int Klim = CK ? (K < brow + 128 ? K : brow + 128) : K;

    int z = blockIdx.z;
    int z1 = z / Z2, z2 = z - z1 * Z2;
    A += (size_t)z1 * sAz1 + (size_t)z2 * sAz2;
    B += (size_t)z1 * sBz1 + (size_t)z2 * sBz2;
    C += (size_t)z1 * sCz1 + (size_t)z2 * sCz2;
    const float* Rp = (EPI == 2) ? R + (size_t)z1 * sCz1 + (size_t)z2 * sCz2 : nullptr;

    __shared__ __align__(16) ushort_t As[128 * 32];
    __shared__ __align__(16) ushort_t Bs[BN * 32];

    int tid = threadIdx.x;
    int lane = tid & 63, wid = tid >> 6;
    int wr = (wid >> 1) * 64;
    int wc = (wid & 1) * (FN * 16);
    int fr = lane & 15;
    int kg = (lane >> 4) * 8;

    // staging addresses: thread covers (row = tid/4, k = (tid&3)*8), 16B each.
    // B rows clamped to N-1 (OOB columns masked at epilogue; avoids garbage reads).
    int br1 = bcol + (tid >> 2);      if (br1 > N - 1) br1 = N - 1;
    int br2 = bcol + 64 + (tid >> 2); if (br2 > N - 1) br2 = N - 1;
    const ushort_t* Ag  = A + (size_t)(brow + (tid >> 2)) * lda + ((tid & 3) << 3);
    const ushort_t* Ag2 = Ag + (size_t)64 * lda;
    ushort_t* Al  = As + tid * 8;
    ushort_t* Al2 = As + 2048 + tid * 8;
    const ushort_t* Bg  = B + (size_t)br1 * ldb + ((tid & 3) << 3);
    const ushort_t* Bg2 = B + (size_t)br2 * ldb + ((tid & 3) << 3);
    ushort_t* Bl  = Bs + tid * 8;
    ushort_t* Bl2 = Bs + 2048 + tid * 8;

    f32x4 acc[4][FN] = {};

    for (int k0 = 0; k0 < Klim; k0 += 32) {
        gld16(Ag + k0, Al);
        gld16(Ag2 + k0, Al2);
        gld16(Bg + k0, Bl);
        if constexpr (BN == 128) gld16(Bg2 + k0, Bl2);
        __syncthreads();
        bf16x8 af[4], bfv[FN];
#pragma unroll
        for (int m = 0; m < 4; m++)
            af[m] = *(const bf16x8*)(As + (wr + m * 16 + fr) * 32 + kg);
#pragma unroll
        for (int n = 0; n < FN; n++)
            bfv[n] = *(const bf16x8*)(Bs + (wc + n * 16 + fr) * 32 + kg);
#pragma unroll
        for (int m = 0; m < 4; m++)
#pragma unroll
            for (int n = 0; n < FN; n++)
                acc[m][n] = __builtin_amdgcn_mfma_f32_16x16x32_bf16(af[m], bfv[n], acc[m][n], 0, 0, 0);
        __syncthreads();
    }

    int cr = (lane >> 4) * 4;
#pragma unroll
    for (int m = 0; m < 4; m++) {
#pragma unroll
        for (int n = 0; n < FN; n++) {
            int col = bcol + wc + n * 16 + fr;
            if (col < N) {
                float bv = bias ? bias[col] : 0.0f;
#pragma unroll
                for (int i = 0; i < 4; i++) {
                    int row = brow + wr + m * 16 + cr + i;
                    float v = acc[m][n][i] + bv;
                    if constexpr (EPI == 1) v = gelu_f(v);
                    if constexpr (EPI == 2) v += Rp[(size_t)row * ldc + col];
                    store_c(&C[(size_t)row * ldc + col], v);
                }
            }
        }
    }
}

// ---------------------------------------------------------------- launch
extern "C" void kernel_launch(void* const* d_in, const int* in_sizes, int n_in,
                              void* d_out, int out_size, void* d_ws, size_t ws_size,
                              hipStream_t stream) {
    const int*   idx    = (const int*)d_in[0];
    const float* wte    = (const float*)d_in[1];
    const float* wpe    = (const float*)d_in[2];
    const float* ln1_w  = (const float*)d_in[3];
    const float* ln1_b  = (const float*)d_in[4];
    const float* attn_w = (const float*)d_in[5];
    const float* attn_b = (const float*)d_in[6];
    const float* proj_w = (const float*)d_in[7];
    const float* proj_b = (const float*)d_in[8];
    const float* ln2_w  = (const float*)d_in[9];
    const float* ln2_b  = (const float*)d_in[10];
    const float* fc_w   = (const float*)d_in[11];
    const float* fc_b   = (const float*)d_in[12];
    const float* fcp_w  = (const float*)d_in[13];
    const float* fcp_b  = (const float*)d_in[14];
    const float* lnf_w  = (const float*)d_in[15];
    const float* lnf_b  = (const float*)d_in[16];
    float* out = (float*)d_out;

    // workspace layout (~152.6 MB total)
    char* p = (char*)d_ws;
    float*    x    = (float*)p;    p += (size_t)2048 * 768 * 4;
    ushort_t* xn   = (ushort_t*)p; p += (size_t)2048 * 768 * 2;
    ushort_t* qkvb = (ushort_t*)p; p += (size_t)2048 * 2304 * 2;
    ushort_t* y    = (ushort_t*)p; p += (size_t)2048 * 768 * 2;
    ushort_t* h    = (ushort_t*)p; p += (size_t)2048 * 3072 * 2;
    ushort_t* vt   = (ushort_t*)p; p += (size_t)24 * 64 * 1024 * 2;
    float*    S    = (float*)p;    p += (size_t)24 * 1024 * 1024 * 4;
    ushort_t* wteb = (ushort_t*)S;   // alias: S dead after layer loop (77.2MB < 100.7MB)
    ushort_t* awT  = (ushort_t*)p; p += (size_t)2304 * 768 * 2;   // per-layer
    ushort_t* pwT  = (ushort_t*)p; p += (size_t)768 * 768 * 2;
    ushort_t* fwT  = (ushort_t*)p; p += (size_t)3072 * 768 * 2;
    ushort_t* fpwT = (ushort_t*)p; p += (size_t)768 * 3072 * 2;

    const long long sQz1 = 1024LL * 2304, sQz2 = 64;     // qkv (b, h) strides
    const long long sS1 = 12LL * 1024 * 1024, sS2 = 1024LL * 1024;

    embed_kernel<<<2048, 192, 0, stream>>>(idx, wte, wpe, x);

    for (int l = 0; l < 12; l++) {
        ln_kernel<<<2048, 256, 0, stream>>>(x, ln1_w + l * 768, ln1_b + l * 768, xn);
        transpose_w<<<dim3(36, 12, 1), 256, 0, stream>>>(
            attn_w + (size_t)l * 768 * 2304, awT, 768, 2304);
        // qkv[2048,2304] = xn @ awT^T + b
        gemm2<128, 0, false, false, ushort_t><<<dim3(18, 16, 1), 256, 0, stream>>>(
            xn, 768, 0, 0,
            awT, 768, 0, 0,
            qkvb, 2304, 0, 0,
            attn_b + l * 2304, nullptr, 2048, 2304, 768, 1);
        // S = Q @ K^T  per (b,h)
        gemm2<128, 0, true, false, float><<<dim3(8, 8, 24), 256, 0, stream>>>(
            qkvb, 2304, sQz1, sQz2,
            qkvb + 768, 2304, sQz1, sQz2,
            S, 1024, sS1, sS2,
            nullptr, nullptr, 1024, 1024, 64, 12);
        softmax_kernel<<<24 * 1024, 256, 0, stream>>>(S);
        vtrans_kernel<<<dim3(16, 24), 256, 0, stream>>>(qkvb, vt);
        // y = P @ V  per (b,h):  A=P bf16 (lda=2048 ushorts), B=vt [64,1024]
        gemm2<64, 0, true, false, ushort_t><<<dim3(1, 8, 24), 256, 0, stream>>>(
            (const ushort_t*)S, 2048, 2 * sS1, 2 * sS2,
            vt, 1024, 12LL * 64 * 1024, 64LL * 1024,
            y, 768, 1024LL * 768, 64,
            nullptr, nullptr, 1024, 64, 1024, 12);
        transpose_w<<<dim3(12, 12, 1), 256, 0, stream>>>(
            proj_w + (size_t)l * 768 * 768, pwT, 768, 768);
        // x += y @ pwT^T + b
        gemm2<128, 2, false, false, float><<<dim3(6, 16, 1), 256, 0, stream>>>(
            y, 768, 0, 0,
            pwT, 768, 0, 0,
            x, 768, 0, 0,
            proj_b + l * 768, x, 2048, 768, 768, 1);
        ln_kernel<<<2048, 256, 0, stream>>>(x, ln2_w + l * 768, ln2_b + l * 768, xn);
        transpose_w<<<dim3(48, 12, 1), 256, 0, stream>>>(
            fc_w + (size_t)l * 768 * 3072, fwT, 768, 3072);
        // h = gelu(xn @ fwT^T + b)
        gemm2<128, 1, false, false, ushort_t><<<dim3(24, 16, 1), 256, 0, stream>>>(
            xn, 768, 0, 0,
            fwT, 768, 0, 0,
            h, 3072, 0, 0,
            fc_b + l * 3072, nullptr, 2048, 3072, 768, 1);
        transpose_w<<<dim3(12, 48, 1), 256, 0, stream>>>(
            fcp_w + (size_t)l * 3072 * 768, fpwT, 3072, 768);
        // x += h @ fpwT^T + b
        gemm2<128, 2, false, false, float><<<dim3(6, 16, 1), 256, 0, stream>>>(
            h, 3072, 0, 0,
            fpwT, 3072, 0, 0,
            x, 768, 0, 0,
            fcp_b + l * 768, x, 2048, 768, 3072, 1);
    }

    // wte -> bf16 into dead S region, then lm-head
    convert_bf<<<4096, 256, 0, stream>>>(wte, wteb, (50257LL * 768) / 8);
    ln_kernel<<<2048, 256, 0, stream>>>(x, lnf_w, lnf_b, xn);
    gemm2<128, 0, false, true, float><<<dim3(16, 393, 1), 256, 0, stream>>>(
        xn, 768, 0, 0,
        wteb, 768, 0, 0,
        out, 50257, 0, 0,
        nullptr, nullptr, 2048, 50257, 768, 1);
}